// Round 5
// baseline (90.732 us; speedup 1.0000x reference)
//
#include <hip/hip_runtime.h>

#define NRULE 100
#define NB    32
#define NE    15000
#define NTOT  (NB * NE)        // 480000
#define NWROW (NTOT / 64)      // 7500 words per rule row
#define NWORDS (NRULE * NWROW) // 750000
#define HD    16
#define KMID  128
#define LN_EPS 1e-5f

typedef float v2f __attribute__((ext_vector_type(2)));
typedef unsigned long long u64;

// ---------------- cvec precompute: c[k] = b1[k] + sum_h rel[h]*W1[(16+h)*128+k]
__global__ void precompute_c_kernel(const long long* __restrict__ all_r,
                                    const float* __restrict__ relemb,
                                    const float* __restrict__ W1,
                                    const float* __restrict__ b1,
                                    float* __restrict__ cvec)
{
    const int k = threadIdx.x;
    if (k >= KMID) return;
    const int r = (int)all_r[0];
    float t = b1[k];
#pragma unroll
    for (int h = 0; h < HD; ++h)
        t = fmaf(relemb[r * HD + h], W1[(HD + h) * KMID + k], t);
    cvec[k] = t;
}

// ---------------- pass 1: bit-pack rc (0/1 ints) into 64-bit words, sequential stream
__global__ __launch_bounds__(256) void pack_kernel(const int* __restrict__ rc,
                                                   u64* __restrict__ bm)
{
    const int lane = threadIdx.x & 63;
    const int gw   = (blockIdx.x * blockDim.x + threadIdx.x) >> 6;  // global wave
    const int nw   = (gridDim.x * blockDim.x) >> 6;
    const int chunk = (NWORDS + nw - 1) / nw;
    int W  = gw * chunk;
    int We = W + chunk; if (We > NWORDS) We = NWORDS;

    // unrolled-by-8: 8 independent 256B wave-loads in flight, contiguous stream per wave
    for (; W + 8 <= We; W += 8) {
        int v[8];
#pragma unroll
        for (int i = 0; i < 8; ++i)
            v[i] = rc[(W + i) * 64 + lane];
#pragma unroll
        for (int i = 0; i < 8; ++i) {
            const u64 m = __ballot(v[i] != 0);
            if (lane == 0) bm[W + i] = m;
        }
    }
    for (; W < We; ++W) {
        const int v = rc[W * 64 + lane];
        const u64 m = __ballot(v != 0);
        if (lane == 0) bm[W] = m;
    }
}

// ---------------- pass 2: compute from bits. 2 elements/thread.
__global__ __launch_bounds__(256) void predictor_bits_kernel(
    const u64*   __restrict__ bm,     // [100][7500]
    const float* __restrict__ remb,   // [100][16]
    const float* __restrict__ ln_g,
    const float* __restrict__ ln_b,
    const float* __restrict__ W1,     // [32][128]; rows 0..15 used
    const float* __restrict__ W2,     // [128]
    const float* __restrict__ b2,     // [1]
    const float* __restrict__ bias,   // [E]
    const float* __restrict__ cvec,   // [128]
    float* __restrict__ out)          // [B*E]
{
    const int tid = blockIdx.x * blockDim.x + threadIdx.x;
    if (tid >= NTOT / 2) return;
    const int word = tid >> 5;          // element pair's word within a rule row
    const int sh   = (tid & 31) * 2;    // bit offset of element 2*tid within the word

    v2f acc[2][8];
#pragma unroll
    for (int e = 0; e < 2; ++e)
#pragma unroll
        for (int hh = 0; hh < 8; ++hh) acc[e][hh] = (v2f){0.f, 0.f};
    u64 om = 0;

    const u64* bp = bm + word;
#pragma unroll 2
    for (int r0 = 0; r0 < NRULE; r0 += 10) {
        u64 s[10];
#pragma unroll
        for (int i = 0; i < 10; ++i)
            s[i] = bp[(r0 + i) * NWROW];
#pragma unroll
        for (int i = 0; i < 10; ++i) {
            om |= s[i];
            const unsigned int sv = (unsigned int)(s[i] >> sh);
            const float f0 = (float)(sv & 1u);
            const float f1 = (float)((sv >> 1) & 1u);
            const v2f f02 = {f0, f0};
            const v2f f12 = {f1, f1};
            const v2f* rb = (const v2f*)(remb + (r0 + i) * HD);   // uniform
#pragma unroll
            for (int hh = 0; hh < 8; ++hh) {
                const v2f w = rb[hh];
                acc[0][hh] = __builtin_elementwise_fma(f02, w, acc[0][hh]);
                acc[1][hh] = __builtin_elementwise_fma(f12, w, acc[1][hh]);
            }
        }
    }

    const float b2v = b2[0];
    const v2f* g2 = (const v2f*)ln_g;
    const v2f* bb2 = (const v2f*)ln_b;
    const v2f* cv2 = (const v2f*)cvec;
    const v2f* w12 = (const v2f*)W1;    // [h][64] v2f
    const v2f* w22 = (const v2f*)W2;
    const v2f zero = {0.f, 0.f};

    float o[2];
#pragma unroll
    for (int e = 0; e < 2; ++e) {
        // LayerNorm over 16 + ReLU
        v2f mu2 = zero;
#pragma unroll
        for (int hh = 0; hh < 8; ++hh) mu2 += acc[e][hh];
        const float mu = (mu2.x + mu2.y) * (1.f / HD);
        const v2f mub = {mu, mu};
        v2f var2 = zero;
#pragma unroll
        for (int hh = 0; hh < 8; ++hh) {
            const v2f d = acc[e][hh] - mub;
            var2 = __builtin_elementwise_fma(d, d, var2);
        }
        const float var = (var2.x + var2.y) * (1.f / HD);
        const float ri = rsqrtf(var + LN_EPS);
        const v2f ri2 = {ri, ri};
#pragma unroll
        for (int hh = 0; hh < 8; ++hh) {
            const v2f t = (acc[e][hh] - mub) * ri2;
            acc[e][hh] = __builtin_elementwise_max(
                __builtin_elementwise_fma(t, g2[hh], bb2[hh]), zero);
        }

        // MLP: o = W2^T relu(W1[0:16]^T vv + c) + b2, packed pairs, mid chunked by 8
        v2f o2 = {b2v, 0.f};
#pragma unroll 1
        for (int kc = 0; kc < KMID; kc += 8) {
            v2f t2[4];
#pragma unroll
            for (int kk = 0; kk < 4; ++kk) t2[kk] = cv2[(kc >> 1) + kk];
#pragma unroll
            for (int h = 0; h < HD; ++h) {
                const v2f av = acc[e][h >> 1];
                const float a = (h & 1) ? av.y : av.x;     // h compile-time
                const v2f a2 = {a, a};
#pragma unroll
                for (int kk = 0; kk < 4; ++kk)
                    t2[kk] = __builtin_elementwise_fma(a2, w12[h * 64 + (kc >> 1) + kk], t2[kk]);
            }
#pragma unroll
            for (int kk = 0; kk < 4; ++kk) {
                const v2f tr = __builtin_elementwise_max(t2[kk], zero);
                o2 = __builtin_elementwise_fma(tr, w22[(kc >> 1) + kk], o2);
            }
        }
        o[e] = o2.x + o2.y;
    }

    // candidate mask + entity bias, 2 consecutive outputs
    const unsigned int omv = (unsigned int)(om >> sh);
    const int base = tid * 2;
    const int m = base % NE;            // base even, NE even
    float2 res;
    res.x = ((omv & 1u) ? o[0] : 0.f) + bias[m];
    res.y = ((omv & 2u) ? o[1] : 0.f) + bias[m + 1];
    *reinterpret_cast<float2*>(out + base) = res;
}

// ---------------- fallback (round-4 proven kernel) if ws too small for bitmat
__global__ __launch_bounds__(256) void predictor_fallback_kernel(
    const int*   __restrict__ rc,
    const float* __restrict__ remb,
    const float* __restrict__ ln_g,
    const float* __restrict__ ln_b,
    const float* __restrict__ W1,
    const float* __restrict__ W2,
    const float* __restrict__ b2,
    const float* __restrict__ bias,
    const float* __restrict__ cvec,
    float* __restrict__ out)
{
    const int tid = blockIdx.x * blockDim.x + threadIdx.x;
    if (tid >= NTOT) return;
    float acc[HD];
#pragma unroll
    for (int h = 0; h < HD; ++h) acc[h] = 0.f;
    float ws = 0.f;
    const int* rcp = rc + tid;
#pragma unroll 2
    for (int r0 = 0; r0 < NRULE; r0 += 10) {
        int v[10];
#pragma unroll
        for (int i = 0; i < 10; ++i) v[i] = rcp[(r0 + i) * NTOT];
#pragma unroll
        for (int i = 0; i < 10; ++i) {
            const float f = (float)v[i];
            ws += f;
#pragma unroll
            for (int h = 0; h < HD; ++h)
                acc[h] = fmaf(f, remb[(r0 + i) * HD + h], acc[h]);
        }
    }
    float mu = 0.f;
#pragma unroll
    for (int h = 0; h < HD; ++h) mu += acc[h];
    mu *= (1.f / HD);
    float var = 0.f;
#pragma unroll
    for (int h = 0; h < HD; ++h) { const float d = acc[h] - mu; var = fmaf(d, d, var); }
    var *= (1.f / HD);
    const float ri = rsqrtf(var + LN_EPS);
#pragma unroll
    for (int h = 0; h < HD; ++h)
        acc[h] = fmaxf(fmaf((acc[h] - mu) * ri, ln_g[h], ln_b[h]), 0.f);
    float o = b2[0];
#pragma unroll 1
    for (int kc = 0; kc < KMID; kc += 8) {
        float t[8];
#pragma unroll
        for (int kk = 0; kk < 8; ++kk) t[kk] = cvec[kc + kk];
#pragma unroll
        for (int h = 0; h < HD; ++h) {
            const float a = acc[h];
#pragma unroll
            for (int kk = 0; kk < 8; ++kk)
                t[kk] = fmaf(a, W1[h * KMID + kc + kk], t[kk]);
        }
#pragma unroll
        for (int kk = 0; kk < 8; ++kk)
            o = fmaf(fmaxf(t[kk], 0.f), W2[kc + kk], o);
    }
    o = (ws > 0.f) ? o : 0.f;
    out[tid] = o + bias[tid % NE];
}

extern "C" void kernel_launch(void* const* d_in, const int* in_sizes, int n_in,
                              void* d_out, int out_size, void* d_ws, size_t ws_size,
                              hipStream_t stream)
{
    const long long* all_r = (const long long*)d_in[1];
    const int*   rc     = (const int*)d_in[2];
    const float* remb   = (const float*)d_in[3];
    const float* relemb = (const float*)d_in[4];
    const float* ln_g   = (const float*)d_in[5];
    const float* ln_b   = (const float*)d_in[6];
    const float* W1     = (const float*)d_in[7];
    const float* b1     = (const float*)d_in[8];
    const float* W2     = (const float*)d_in[9];
    const float* b2     = (const float*)d_in[10];
    const float* bias   = (const float*)d_in[11];
    float* out = (float*)d_out;

    const size_t bm_bytes = (size_t)NWORDS * sizeof(u64);   // 6,000,000
    if (ws_size >= bm_bytes + 512) {
        u64*   bm   = (u64*)d_ws;
        float* cvec = (float*)((char*)d_ws + bm_bytes);
        hipLaunchKernelGGL(precompute_c_kernel, dim3(1), dim3(128), 0, stream,
                           all_r, relemb, W1, b1, cvec);
        hipLaunchKernelGGL(pack_kernel, dim3(1024), dim3(256), 0, stream, rc, bm);
        const int threads = NTOT / 2;                 // 240000
        const int blocks  = (threads + 255) / 256;    // 938
        hipLaunchKernelGGL(predictor_bits_kernel, dim3(blocks), dim3(256), 0, stream,
                           bm, remb, ln_g, ln_b, W1, W2, b2, bias, cvec, out);
    } else {
        float* cvec = (float*)d_ws;
        hipLaunchKernelGGL(precompute_c_kernel, dim3(1), dim3(128), 0, stream,
                           all_r, relemb, W1, b1, cvec);
        const int blocks = (NTOT + 255) / 256;
        hipLaunchKernelGGL(predictor_fallback_kernel, dim3(blocks), dim3(256), 0, stream,
                           rc, remb, ln_g, ln_b, W1, W2, b2, bias, cvec, out);
    }
}

// Round 6
// 86.539 us; speedup vs baseline: 1.0485x; 1.0485x over previous
//
#include <hip/hip_runtime.h>

#define NRULE 100
#define NB    32
#define NE    15000
#define NTOT  (NB * NE)        // 480000
#define NBLK  (NTOT / 256)     // 1875 256-element blocks per rule
#define NQUAD (NRULE * NBLK)   // 187500 word-quads (each = 256 elements)
#define NWORDS (NQUAD * 4)     // 750000 u64 words
#define HD    16
#define KMID  128
#define LN_EPS 1e-5f

typedef float v2f __attribute__((ext_vector_type(2)));
typedef unsigned long long u64;

// ---------------- cvec precompute: c[k] = b1[k] + sum_h rel[h]*W1[(16+h)*128+k]
__global__ void precompute_c_kernel(const long long* __restrict__ all_r,
                                    const float* __restrict__ relemb,
                                    const float* __restrict__ W1,
                                    const float* __restrict__ b1,
                                    float* __restrict__ cvec)
{
    const int k = threadIdx.x;
    if (k >= KMID) return;
    const int r = (int)all_r[0];
    float t = b1[k];
#pragma unroll
    for (int h = 0; h < HD; ++h)
        t = fmaf(relemb[r * HD + h], W1[(HD + h) * KMID + k], t);
    cvec[k] = t;
}

// ---------------- pass 1: bit-pack with int4 (16B/lane, 1KB/wave) streaming loads.
// Quad layout: quad q covers flat rc elements [q*256, q*256+256).
// Word q*4+j, bit L  <->  element q*256 + 4L + j.
__global__ __launch_bounds__(256) void pack_kernel(const int* __restrict__ rc,
                                                   u64* __restrict__ bm)
{
    const int lane = threadIdx.x & 63;
    const int wv   = (blockIdx.x * blockDim.x + threadIdx.x) >> 6;
    const int nwv  = (gridDim.x * blockDim.x) >> 6;
    const int chunk = (NQUAD + nwv - 1) / nwv;
    int W  = wv * chunk;
    int We = W + chunk; if (We > NQUAD) We = NQUAD;

    for (; W + 8 <= We; W += 8) {
        int4 v[8];
#pragma unroll
        for (int i = 0; i < 8; ++i)
            v[i] = *reinterpret_cast<const int4*>(rc + (size_t)(W + i) * 256 + lane * 4);
#pragma unroll
        for (int i = 0; i < 8; ++i) {
            const u64 m0 = __ballot(v[i].x != 0);
            const u64 m1 = __ballot(v[i].y != 0);
            const u64 m2 = __ballot(v[i].z != 0);
            const u64 m3 = __ballot(v[i].w != 0);
            if (lane == 0) {
                *reinterpret_cast<ulonglong2*>(bm + (size_t)(W + i) * 4)     = make_ulonglong2(m0, m1);
                *reinterpret_cast<ulonglong2*>(bm + (size_t)(W + i) * 4 + 2) = make_ulonglong2(m2, m3);
            }
        }
    }
    for (; W < We; ++W) {
        const int4 v = *reinterpret_cast<const int4*>(rc + (size_t)W * 256 + lane * 4);
        const u64 m0 = __ballot(v.x != 0);
        const u64 m1 = __ballot(v.y != 0);
        const u64 m2 = __ballot(v.z != 0);
        const u64 m3 = __ballot(v.w != 0);
        if (lane == 0) {
            *reinterpret_cast<ulonglong2*>(bm + (size_t)W * 4)     = make_ulonglong2(m0, m1);
            *reinterpret_cast<ulonglong2*>(bm + (size_t)W * 4 + 2) = make_ulonglong2(m2, m3);
        }
    }
}

// ---------------- pass 2: compute from bits, 2 consecutive elements/thread.
__global__ __launch_bounds__(256) void predictor_bits_kernel(
    const u64*   __restrict__ bm,     // [100][1875][4] words
    const float* __restrict__ remb,   // [100][16]
    const float* __restrict__ ln_g,
    const float* __restrict__ ln_b,
    const float* __restrict__ W1,     // [32][128]; rows 0..15 used
    const float* __restrict__ W2,     // [128]
    const float* __restrict__ b2,     // [1]
    const float* __restrict__ bias,   // [E]
    const float* __restrict__ cvec,   // [128]
    float* __restrict__ out)          // [B*E]
{
    const int tid = blockIdx.x * blockDim.x + threadIdx.x;
    if (tid >= NTOT / 2) return;
    const int e   = tid * 2;
    const int blk = e >> 8;
    const int pos = e & 255;
    const int L   = pos >> 2;       // bit index, same for e and e+1
    const int jj  = pos & 3;        // 0 or 2; words jj, jj+1 hold e, e+1

    v2f acc[2][8];
#pragma unroll
    for (int ee = 0; ee < 2; ++ee)
#pragma unroll
        for (int hh = 0; hh < 8; ++hh) acc[ee][hh] = (v2f){0.f, 0.f};
    u64 om0 = 0, om1 = 0;

    const u64* bp = bm + (size_t)blk * 4 + jj;
#pragma unroll 2
    for (int r0 = 0; r0 < NRULE; r0 += 5) {
        ulonglong2 s[5];
#pragma unroll
        for (int i = 0; i < 5; ++i)
            s[i] = *reinterpret_cast<const ulonglong2*>(bp + (size_t)(r0 + i) * (NBLK * 4));
#pragma unroll
        for (int i = 0; i < 5; ++i) {
            om0 |= s[i].x; om1 |= s[i].y;
            const float f0 = (float)((unsigned int)(s[i].x >> L) & 1u);
            const float f1 = (float)((unsigned int)(s[i].y >> L) & 1u);
            const v2f f02 = {f0, f0};
            const v2f f12 = {f1, f1};
            const v2f* rb = (const v2f*)(remb + (r0 + i) * HD);   // uniform -> SGPR
#pragma unroll
            for (int hh = 0; hh < 8; ++hh) {
                const v2f w = rb[hh];
                acc[0][hh] = __builtin_elementwise_fma(f02, w, acc[0][hh]);
                acc[1][hh] = __builtin_elementwise_fma(f12, w, acc[1][hh]);
            }
        }
    }

    const float b2v = b2[0];
    const v2f* g2  = (const v2f*)ln_g;
    const v2f* bb2 = (const v2f*)ln_b;
    const v2f* cv2 = (const v2f*)cvec;
    const v2f* w12 = (const v2f*)W1;    // [h][64] v2f
    const v2f* w22 = (const v2f*)W2;
    const v2f zero = {0.f, 0.f};

    float o[2];
#pragma unroll
    for (int ee = 0; ee < 2; ++ee) {
        // LayerNorm over 16 + ReLU
        v2f mu2 = zero;
#pragma unroll
        for (int hh = 0; hh < 8; ++hh) mu2 += acc[ee][hh];
        const float mu = (mu2.x + mu2.y) * (1.f / HD);
        const v2f mub = {mu, mu};
        v2f var2 = zero;
#pragma unroll
        for (int hh = 0; hh < 8; ++hh) {
            const v2f d = acc[ee][hh] - mub;
            var2 = __builtin_elementwise_fma(d, d, var2);
        }
        const float var = (var2.x + var2.y) * (1.f / HD);
        const float ri = rsqrtf(var + LN_EPS);
        const v2f ri2 = {ri, ri};
#pragma unroll
        for (int hh = 0; hh < 8; ++hh) {
            const v2f t = (acc[ee][hh] - mub) * ri2;
            acc[ee][hh] = __builtin_elementwise_max(
                __builtin_elementwise_fma(t, g2[hh], bb2[hh]), zero);
        }

        // MLP: o = W2^T relu(W1[0:16]^T vv + c) + b2, packed pairs, mid chunked by 8
        v2f o2 = {b2v, 0.f};
#pragma unroll 1
        for (int kc = 0; kc < KMID; kc += 8) {
            v2f t2[4];
#pragma unroll
            for (int kk = 0; kk < 4; ++kk) t2[kk] = cv2[(kc >> 1) + kk];
#pragma unroll
            for (int h = 0; h < HD; ++h) {
                const v2f av = acc[ee][h >> 1];
                const float a = (h & 1) ? av.y : av.x;     // h compile-time
                const v2f a2 = {a, a};
#pragma unroll
                for (int kk = 0; kk < 4; ++kk)
                    t2[kk] = __builtin_elementwise_fma(a2, w12[h * 64 + (kc >> 1) + kk], t2[kk]);
            }
#pragma unroll
            for (int kk = 0; kk < 4; ++kk) {
                const v2f tr = __builtin_elementwise_max(t2[kk], zero);
                o2 = __builtin_elementwise_fma(tr, w22[(kc >> 1) + kk], o2);
            }
        }
        o[ee] = o2.x + o2.y;
    }

    const int m = e % NE;               // e even, NE even
    float2 res;
    res.x = (((unsigned int)(om0 >> L) & 1u) ? o[0] : 0.f) + bias[m];
    res.y = (((unsigned int)(om1 >> L) & 1u) ? o[1] : 0.f) + bias[m + 1];
    *reinterpret_cast<float2*>(out + e) = res;
}

// ---------------- fallback (round-3 proven kernel) if ws too small for bitmat
__global__ __launch_bounds__(256) void predictor_fallback_kernel(
    const int*   __restrict__ rc,
    const float* __restrict__ remb,
    const float* __restrict__ ln_g,
    const float* __restrict__ ln_b,
    const float* __restrict__ W1,
    const float* __restrict__ W2,
    const float* __restrict__ b2,
    const float* __restrict__ bias,
    const float* __restrict__ cvec,
    float* __restrict__ out)
{
    const int tid = blockIdx.x * blockDim.x + threadIdx.x;
    if (tid >= NTOT) return;
    float acc[HD];
#pragma unroll
    for (int h = 0; h < HD; ++h) acc[h] = 0.f;
    float ws = 0.f;
    const int* rcp = rc + tid;
#pragma unroll 2
    for (int r0 = 0; r0 < NRULE; r0 += 10) {
        int v[10];
#pragma unroll
        for (int i = 0; i < 10; ++i) v[i] = rcp[(r0 + i) * NTOT];
#pragma unroll
        for (int i = 0; i < 10; ++i) {
            const float f = (float)v[i];
            ws += f;
#pragma unroll
            for (int h = 0; h < HD; ++h)
                acc[h] = fmaf(f, remb[(r0 + i) * HD + h], acc[h]);
        }
    }
    float mu = 0.f;
#pragma unroll
    for (int h = 0; h < HD; ++h) mu += acc[h];
    mu *= (1.f / HD);
    float var = 0.f;
#pragma unroll
    for (int h = 0; h < HD; ++h) { const float d = acc[h] - mu; var = fmaf(d, d, var); }
    var *= (1.f / HD);
    const float ri = rsqrtf(var + LN_EPS);
#pragma unroll
    for (int h = 0; h < HD; ++h)
        acc[h] = fmaxf(fmaf((acc[h] - mu) * ri, ln_g[h], ln_b[h]), 0.f);
    float o = b2[0];
#pragma unroll 1
    for (int kc = 0; kc < KMID; kc += 8) {
        float t[8];
#pragma unroll
        for (int kk = 0; kk < 8; ++kk) t[kk] = cvec[kc + kk];
#pragma unroll
        for (int h = 0; h < HD; ++h) {
            const float a = acc[h];
#pragma unroll
            for (int kk = 0; kk < 8; ++kk)
                t[kk] = fmaf(a, W1[h * KMID + kc + kk], t[kk]);
        }
#pragma unroll
        for (int kk = 0; kk < 8; ++kk)
            o = fmaf(fmaxf(t[kk], 0.f), W2[kc + kk], o);
    }
    o = (ws > 0.f) ? o : 0.f;
    out[tid] = o + bias[tid % NE];
}

extern "C" void kernel_launch(void* const* d_in, const int* in_sizes, int n_in,
                              void* d_out, int out_size, void* d_ws, size_t ws_size,
                              hipStream_t stream)
{
    const long long* all_r = (const long long*)d_in[1];
    const int*   rc     = (const int*)d_in[2];
    const float* remb   = (const float*)d_in[3];
    const float* relemb = (const float*)d_in[4];
    const float* ln_g   = (const float*)d_in[5];
    const float* ln_b   = (const float*)d_in[6];
    const float* W1     = (const float*)d_in[7];
    const float* b1     = (const float*)d_in[8];
    const float* W2     = (const float*)d_in[9];
    const float* b2     = (const float*)d_in[10];
    const float* bias   = (const float*)d_in[11];
    float* out = (float*)d_out;

    const size_t bm_bytes = (size_t)NWORDS * sizeof(u64);   // 6,000,000
    if (ws_size >= bm_bytes + 512) {
        u64*   bm   = (u64*)d_ws;
        float* cvec = (float*)((char*)d_ws + bm_bytes);
        hipLaunchKernelGGL(precompute_c_kernel, dim3(1), dim3(128), 0, stream,
                           all_r, relemb, W1, b1, cvec);
        hipLaunchKernelGGL(pack_kernel, dim3(2048), dim3(256), 0, stream, rc, bm);
        const int threads = NTOT / 2;                 // 240000
        const int blocks  = (threads + 255) / 256;    // 938
        hipLaunchKernelGGL(predictor_bits_kernel, dim3(blocks), dim3(256), 0, stream,
                           bm, remb, ln_g, ln_b, W1, W2, b2, bias, cvec, out);
    } else {
        float* cvec = (float*)d_ws;
        hipLaunchKernelGGL(precompute_c_kernel, dim3(1), dim3(128), 0, stream,
                           all_r, relemb, W1, b1, cvec);
        const int blocks = (NTOT + 255) / 256;
        hipLaunchKernelGGL(predictor_fallback_kernel, dim3(blocks), dim3(256), 0, stream,
                           rc, remb, ln_g, ln_b, W1, W2, b2, bias, cvec, out);
    }
}

// Round 7
// 62.521 us; speedup vs baseline: 1.4512x; 1.3842x over previous
//
#include <hip/hip_runtime.h>

#define NRULE 100
#define NB    32
#define NE    15000
#define NTOT  (NB * NE)   // 480000
#define HD    16
#define KMID  128
#define LN_EPS 1e-5f
#define RCHUNK 10

typedef float v2f __attribute__((ext_vector_type(2)));

// Precompute c[k] = b1[k] + sum_h rel[h] * W1[(16+h)*128 + k]
__global__ void precompute_c_kernel(const long long* __restrict__ all_r,
                                    const float* __restrict__ relemb,
                                    const float* __restrict__ W1,
                                    const float* __restrict__ b1,
                                    float* __restrict__ cvec)
{
    const int k = threadIdx.x;
    if (k >= KMID) return;
    const int r = (int)all_r[0];
    float t = b1[k];
#pragma unroll
    for (int h = 0; h < HD; ++h)
        t = fmaf(relemb[r * HD + h], W1[(HD + h) * KMID + k], t);
    cvec[k] = t;
}

// Fused: stream rc once (int2/lane), packed-v2f math hidden under the read.
__global__ __launch_bounds__(256) void predictor_main_kernel(
    const int*   __restrict__ rc,     // [R, B*E]
    const float* __restrict__ remb,   // [R, 16]
    const float* __restrict__ ln_g,
    const float* __restrict__ ln_b,
    const float* __restrict__ W1,     // [32, 128]; rows 0..15 used
    const float* __restrict__ W2,     // [128]
    const float* __restrict__ b2,     // [1]
    const float* __restrict__ bias,   // [E]
    const float* __restrict__ cvec,   // [128]
    float* __restrict__ out)          // [B*E]
{
    const int tid  = blockIdx.x * blockDim.x + threadIdx.x;
    const int base = tid * 2;
    if (base >= NTOT) return;

    v2f acc[2][8];
#pragma unroll
    for (int e = 0; e < 2; ++e)
#pragma unroll
        for (int hh = 0; hh < 8; ++hh) acc[e][hh] = (v2f){0.f, 0.f};
    int c0 = 0, c1 = 0;

    const int* rcp = rc + base;
#pragma unroll 2
    for (int r0 = 0; r0 < NRULE; r0 += RCHUNK) {
        int2 v[RCHUNK];
#pragma unroll
        for (int i = 0; i < RCHUNK; ++i)
            v[i] = *reinterpret_cast<const int2*>(rcp + (r0 + i) * NTOT);
#pragma unroll
        for (int i = 0; i < RCHUNK; ++i) {
            c0 |= v[i].x; c1 |= v[i].y;
            const float f0 = (float)v[i].x;
            const float f1 = (float)v[i].y;
            const v2f f02 = {f0, f0};
            const v2f f12 = {f1, f1};
            const v2f* rb = (const v2f*)(remb + (r0 + i) * HD);   // uniform -> SGPR
#pragma unroll
            for (int hh = 0; hh < 8; ++hh) {
                const v2f w = rb[hh];
                acc[0][hh] = __builtin_elementwise_fma(f02, w, acc[0][hh]);
                acc[1][hh] = __builtin_elementwise_fma(f12, w, acc[1][hh]);
            }
        }
    }

    const float b2v = b2[0];
    const v2f* g2  = (const v2f*)ln_g;
    const v2f* bb2 = (const v2f*)ln_b;
    const v2f* cv2 = (const v2f*)cvec;
    const v2f* w12 = (const v2f*)W1;    // [h][64] v2f
    const v2f* w22 = (const v2f*)W2;
    const v2f zero = {0.f, 0.f};

    float o[2];
#pragma unroll
    for (int e = 0; e < 2; ++e) {
        // LayerNorm over 16 + ReLU (packed)
        v2f mu2 = zero;
#pragma unroll
        for (int hh = 0; hh < 8; ++hh) mu2 += acc[e][hh];
        const float mu = (mu2.x + mu2.y) * (1.f / HD);
        const v2f mub = {mu, mu};
        v2f var2 = zero;
#pragma unroll
        for (int hh = 0; hh < 8; ++hh) {
            const v2f d = acc[e][hh] - mub;
            var2 = __builtin_elementwise_fma(d, d, var2);
        }
        const float var = (var2.x + var2.y) * (1.f / HD);
        const float ri = rsqrtf(var + LN_EPS);
        const v2f ri2 = {ri, ri};
#pragma unroll
        for (int hh = 0; hh < 8; ++hh) {
            const v2f t = (acc[e][hh] - mub) * ri2;
            acc[e][hh] = __builtin_elementwise_max(
                __builtin_elementwise_fma(t, g2[hh], bb2[hh]), zero);
        }

        // MLP: o = W2^T relu(W1[0:16]^T vv + c) + b2 (packed, mid chunked by 8)
        v2f o2 = {b2v, 0.f};
#pragma unroll 1
        for (int kc = 0; kc < KMID; kc += 8) {
            v2f t2[4];
#pragma unroll
            for (int kk = 0; kk < 4; ++kk) t2[kk] = cv2[(kc >> 1) + kk];
#pragma unroll
            for (int h = 0; h < HD; ++h) {
                const v2f av = acc[e][h >> 1];
                const float a = (h & 1) ? av.y : av.x;     // h compile-time
                const v2f a2 = {a, a};
#pragma unroll
                for (int kk = 0; kk < 4; ++kk)
                    t2[kk] = __builtin_elementwise_fma(a2, w12[h * 64 + (kc >> 1) + kk], t2[kk]);
            }
#pragma unroll
            for (int kk = 0; kk < 4; ++kk) {
                const v2f tr = __builtin_elementwise_max(t2[kk], zero);
                o2 = __builtin_elementwise_fma(tr, w22[(kc >> 1) + kk], o2);
            }
        }
        o[e] = o2.x + o2.y;
    }

    const int m = base % NE;            // base even, NE even
    float2 res;
    res.x = ((c0 != 0) ? o[0] : 0.f) + bias[m];
    res.y = ((c1 != 0) ? o[1] : 0.f) + bias[m + 1];
    *reinterpret_cast<float2*>(out + base) = res;
}

extern "C" void kernel_launch(void* const* d_in, const int* in_sizes, int n_in,
                              void* d_out, int out_size, void* d_ws, size_t ws_size,
                              hipStream_t stream)
{
    const long long* all_r = (const long long*)d_in[1];
    const int*   rc     = (const int*)d_in[2];
    const float* remb   = (const float*)d_in[3];
    const float* relemb = (const float*)d_in[4];
    const float* ln_g   = (const float*)d_in[5];
    const float* ln_b   = (const float*)d_in[6];
    const float* W1     = (const float*)d_in[7];
    const float* b1     = (const float*)d_in[8];
    const float* W2     = (const float*)d_in[9];
    const float* b2     = (const float*)d_in[10];
    const float* bias   = (const float*)d_in[11];
    float* out  = (float*)d_out;
    float* cvec = (float*)d_ws;

    hipLaunchKernelGGL(precompute_c_kernel, dim3(1), dim3(128), 0, stream,
                       all_r, relemb, W1, b1, cvec);

    const int threads = NTOT / 2;                 // 240000
    const int blocks  = (threads + 255) / 256;    // 938
    hipLaunchKernelGGL(predictor_main_kernel, dim3(blocks), dim3(256), 0, stream,
                       rc, remb, ln_g, ln_b, W1, W2, b2, bias, cvec, out);
}